// Round 9
// baseline (71.957 us; speedup 1.0000x reference)
//
#include <hip/hip_runtime.h>
#include <math.h>

#define NXg 512
#define NYg 512
#define NSEG (NXg * NYg)   // 262144 = 2^18
#define CCH 64
#define CAP 16             // bucket capacity per pillar (lambda~0.36)
#define LDSK 8             // points staged in LDS per pillar (k>8 ~never)
#define PSTR 9             // LDS point-slot stride
#define PPB 128            // pillars per block
#define TSTR 129           // tile stride [c][p]
#define NXCD 8
#define BN_EPS 1e-3f

// grid constants (f32, as in the reference arrays)
#define PCMINX (-51.2f)
#define PCMINY (-51.2f)
#define PCMINZ (-3.0f)
#define PCMAXX (51.2f)
#define PCMAXY (51.2f)
#define PCMAXZ (3.0f)
#define VOXX (0.2f)
#define VOXY (0.2f)
#define VOXZ (6.0f)

// f32-exact reciprocals (XLA fast-math computes (p-min)*(1/voxel) in f32).
#define RECIPX 5.0f
#define RECIPY 5.0f
#define RECIPZ (__uint_as_float(0x3E2AAAABu))   // (float)(1/6.0f)

__device__ __forceinline__ int calc_pid(float x, float y, float z) {
    bool in_range = (x >= PCMINX) && (x < PCMAXX) &&
                    (y >= PCMINY) && (y < PCMAXY) &&
                    (z >= PCMINZ) && (z < PCMAXZ);
    if (!in_range) return -1;
    int cx = (int)floorf((x - PCMINX) * RECIPX);
    int cy = (int)floorf((y - PCMINY) * RECIPY);
    int p = cy * NXg + cx;
    return (p >= 0 && p < NSEG) ? p : -1;
}

// K1: bin point COORDINATES into fixed-capacity per-pillar buckets (float4).
__global__ void k1_bin(const float* __restrict__ pts, unsigned* __restrict__ cnt,
                       float4* __restrict__ bucket, int B, int N) {
    int i = blockIdx.x * blockDim.x + threadIdx.x;
    if (i >= B * N) return;
    const float* p = pts + (size_t)i * 3;
    float x = p[0], y = p[1], z = p[2];
    int pd = calc_pid(x, y, z);
    if (pd < 0) return;
    int b = i / N;
    int g = b * NSEG + pd;
    unsigned slot = atomicAdd(&cnt[g], 1u);
    if (slot < CAP) {
        float4 e; e.x = x; e.y = y; e.z = z; e.w = 0.0f;
        bucket[(size_t)g * CAP + slot] = e;
    }
}

// K4: block = 128 pillars, XCD-swizzled so each XCD owns a contiguous 1/8 of
// pillar space (write locality). Phase 1 (2 waves): lane-per-pillar gather
// into LDS (first 8 pts; mean over all). Phase 2: wave-per-pillar,
// lane-per-channel PFN from LDS. Phase 3: coalesced float4 canvas write
// (512 B contiguous per channel row per block; every element written).
__global__ void __launch_bounds__(256) k4_compute(
    const unsigned* __restrict__ cnt, const float4* __restrict__ bucket,
    const float* __restrict__ W, const float* __restrict__ gamma,
    const float* __restrict__ beta, const float* __restrict__ rmean,
    const float* __restrict__ rvar, float* __restrict__ out, int nblocks) {
    __shared__ float Ws[9 * CCH];
    __shared__ float scale_s[CCH];
    __shared__ float shift_s[CCH];
    __shared__ float pxs[PPB * PSTR];
    __shared__ float pys[PPB * PSTR];
    __shared__ float pzs[PPB * PSTR];
    __shared__ float mxs[PPB], mys[PPB], mzs[PPB];
    __shared__ int ks[PPB];
    __shared__ float tile[CCH * TSTR];   // [c][p_local]

    int t = threadIdx.x;
    for (int i = t; i < 9 * CCH; i += 256) Ws[i] = W[i];
    if (t < CCH) {
        float sc = gamma[t] * (1.0f / sqrtf(rvar[t] + BN_EPS));
        scale_s[t] = sc;
        shift_s[t] = beta[t] - rmean[t] * sc;
    }

    // bijective XCD swizzle: nblocks % 8 == 0
    int cpx = nblocks / NXCD;
    int bid = (int)blockIdx.x;
    int swz = (bid % NXCD) * cpx + bid / NXCD;
    int gp0 = swz * PPB;               // 128 pillars per block (same batch)

    // ---- phase 1: parallel gather, lane = pillar (2 waves) ----
    if (t < PPB) {
        int gp = gp0 + t;
        const float4* bk = bucket + (size_t)gp * CAP;
        float4 e0 = bk[0];             // independent loads in flight together
        float4 e1 = bk[1];
        unsigned kc = cnt[gp];
        int k = (kc < CAP) ? (int)kc : CAP;
        ks[t] = k;
        float sx = 0.f, sy = 0.f, sz = 0.f;
        if (k > 0) {
            pxs[t * PSTR + 0] = e0.x; pys[t * PSTR + 0] = e0.y; pzs[t * PSTR + 0] = e0.z;
            sx += e0.x; sy += e0.y; sz += e0.z;
        }
        if (k > 1) {
            pxs[t * PSTR + 1] = e1.x; pys[t * PSTR + 1] = e1.y; pzs[t * PSTR + 1] = e1.z;
            sx += e1.x; sy += e1.y; sz += e1.z;
        }
        for (int j = 2; j < k; ++j) {
            float4 e = bk[j];
            if (j < LDSK) {
                pxs[t * PSTR + j] = e.x; pys[t * PSTR + j] = e.y; pzs[t * PSTR + j] = e.z;
            }
            sx += e.x; sy += e.y; sz += e.z;
        }
        float fk = (k > 0) ? (float)k : 1.0f;
        mxs[t] = sx / fk; mys[t] = sy / fk; mzs[t] = sz / fk;
    }
    __syncthreads();

    // ---- phase 2: wave-per-pillar, lane = channel ----
    int lane = t & 63;
    int wave = t >> 6;
    float scale = scale_s[lane];
    float shift = shift_s[lane];
    for (int it = 0; it < PPB / 4; ++it) {
        int ppl = wave * (PPB / 4) + it;
        int k = ks[ppl];
        float accv = 0.0f;
        if (k > 0) {
            float mx = mxs[ppl], my = mys[ppl], mz = mzs[ppl];
            for (int j = 0; j < k; ++j) {
                float x, y, z;
                if (j < LDSK) {
                    x = pxs[ppl * PSTR + j];
                    y = pys[ppl * PSTR + j];
                    z = pzs[ppl * PSTR + j];
                } else {            // ~never taken (P(k>8) ~ 1e-10/pillar)
                    float4 e = bucket[(size_t)(gp0 + ppl) * CAP + j];
                    x = e.x; y = e.y; z = e.z;
                }
                int cx = (int)floorf((x - PCMINX) * RECIPX);
                int cy = (int)floorf((y - PCMINY) * RECIPY);
                int cz = (int)floorf((z - PCMINZ) * RECIPZ);
                float ctx = ((float)cx + 0.5f) * VOXX + PCMINX;
                float cty = ((float)cy + 0.5f) * VOXY + PCMINY;
                float ctz = ((float)cz + 0.5f) * VOXZ + PCMINZ;
                float h;
                h = x * Ws[0 * CCH + lane];
                h = fmaf(y,       Ws[1 * CCH + lane], h);
                h = fmaf(z,       Ws[2 * CCH + lane], h);
                h = fmaf(x - mx,  Ws[3 * CCH + lane], h);
                h = fmaf(y - my,  Ws[4 * CCH + lane], h);
                h = fmaf(z - mz,  Ws[5 * CCH + lane], h);
                h = fmaf(x - ctx, Ws[6 * CCH + lane], h);
                h = fmaf(y - cty, Ws[7 * CCH + lane], h);
                h = fmaf(z - ctz, Ws[8 * CCH + lane], h);
                h = fmaf(h, scale, shift);
                h = fmaxf(h, 0.0f);
                accv += h;
            }
            accv /= (float)k;
        }
        tile[lane * TSTR + ppl] = accv;
    }
    __syncthreads();

    // ---- phase 3: coalesced float4 write-out, 512 B per channel row ----
    int b = gp0 >> 18;                 // NSEG = 2^18
    int pbatch = gp0 & (NSEG - 1);
    size_t obase = (size_t)b * CCH * NSEG + (size_t)pbatch;
    // 64 rows x 32 float4 = 2048 float4, 8 per thread
    for (int j = 0; j < 8; ++j) {
        int idx = j * 256 + t;
        int c = idx >> 5;              // row (channel)
        int q = idx & 31;              // float4 index within row
        float4 v;
        v.x = tile[c * TSTR + q * 4 + 0];
        v.y = tile[c * TSTR + q * 4 + 1];
        v.z = tile[c * TSTR + q * 4 + 2];
        v.w = tile[c * TSTR + q * 4 + 3];
        *reinterpret_cast<float4*>(out + obase + (size_t)c * NSEG + q * 4) = v;
    }
}

extern "C" void kernel_launch(void* const* d_in, const int* in_sizes, int n_in,
                              void* d_out, int out_size, void* d_ws, size_t ws_size,
                              hipStream_t stream) {
    const float* points = (const float*)d_in[0];
    const float* W      = (const float*)d_in[1];
    const float* gamma  = (const float*)d_in[2];
    const float* beta   = (const float*)d_in[3];
    const float* rmean  = (const float*)d_in[4];
    const float* rvar   = (const float*)d_in[5];
    float* out = (float*)d_out;

    int B = out_size / (CCH * NSEG);          // 2
    int N = in_sizes[0] / (3 * B);            // 100000
    int BN = B * NSEG;                        // 524288
    int total_pts = B * N;

    // workspace: cnt [BN] u32 (2 MB) + bucket [BN*CAP] float4 (134 MB)
    unsigned* cnt  = (unsigned*)d_ws;
    float4* bucket = (float4*)(cnt + BN);

    hipMemsetAsync(cnt, 0, (size_t)BN * sizeof(unsigned), stream);

    int blk = 256;
    int grd_pts = (total_pts + blk - 1) / blk;
    k1_bin<<<grd_pts, blk, 0, stream>>>(points, cnt, bucket, B, N);
    int nblocks = BN / PPB;                   // 4096, % 8 == 0
    k4_compute<<<nblocks, blk, 0, stream>>>(cnt, bucket, W, gamma, beta,
                                            rmean, rvar, out, nblocks);
}

// Round 10
// 49.975 us; speedup vs baseline: 1.4399x; 1.4399x over previous
//
#include <hip/hip_runtime.h>
#include <math.h>

#define NXg 512
#define NYg 512
#define NSEG (NXg * NYg)   // 262144 = 2^18
#define CCH 64
#define CAP 16             // bucket capacity per pillar
#define SLOTS 4            // points staged in LDS per pillar (k>4 rare -> global)
#define PSTR 5             // LDS point-slot stride
#define PPB 64             // pillars per block
#define BN_EPS 1e-3f

// grid constants (f32, as in the reference arrays)
#define PCMINX (-51.2f)
#define PCMINY (-51.2f)
#define PCMINZ (-3.0f)
#define PCMAXX (51.2f)
#define PCMAXY (51.2f)
#define PCMAXZ (3.0f)
#define VOXX (0.2f)
#define VOXY (0.2f)
#define VOXZ (6.0f)

// f32-exact reciprocals (XLA fast-math computes (p-min)*(1/voxel) in f32).
#define RECIPX 5.0f
#define RECIPY 5.0f
#define RECIPZ (__uint_as_float(0x3E2AAAABu))   // (float)(1/6.0f)

__device__ __forceinline__ int calc_pid(float x, float y, float z) {
    bool in_range = (x >= PCMINX) && (x < PCMAXX) &&
                    (y >= PCMINY) && (y < PCMAXY) &&
                    (z >= PCMINZ) && (z < PCMAXZ);
    if (!in_range) return -1;
    int cx = (int)floorf((x - PCMINX) * RECIPX);
    int cy = (int)floorf((y - PCMINY) * RECIPY);
    int p = cy * NXg + cx;
    return (p >= 0 && p < NSEG) ? p : -1;
}

// K1: bin point COORDINATES into fixed-capacity per-pillar buckets (float4).
__global__ void k1_bin(const float* __restrict__ pts, unsigned* __restrict__ cnt,
                       float4* __restrict__ bucket, int B, int N) {
    int i = blockIdx.x * blockDim.x + threadIdx.x;
    if (i >= B * N) return;
    const float* p = pts + (size_t)i * 3;
    float x = p[0], y = p[1], z = p[2];
    int pd = calc_pid(x, y, z);
    if (pd < 0) return;
    int b = i / N;
    int g = b * NSEG + pd;
    unsigned slot = atomicAdd(&cnt[g], 1u);
    if (slot < CAP) {
        float4 e; e.x = x; e.y = y; e.z = z; e.w = 0.0f;
        bucket[(size_t)g * CAP + slot] = e;
    }
}

// K4: block = 64 pillars. Phase 1: 256-thread gather (thread = pillar x slot),
// 4-lane shuffle reduce for the mean. Phase 2: wave-per-pillar, lane-per-
// channel folded PFN (weights in registers). Phase 3: coalesced float4 write.
__global__ void __launch_bounds__(256) k4_compute(
    const unsigned* __restrict__ cnt, const float4* __restrict__ bucket,
    const float* __restrict__ W, const float* __restrict__ gamma,
    const float* __restrict__ beta, const float* __restrict__ rmean,
    const float* __restrict__ rvar, float* __restrict__ out) {
    __shared__ float pxs[PPB * PSTR];
    __shared__ float pys[PPB * PSTR];
    __shared__ float pzs[PPB * PSTR];
    __shared__ float mxs[PPB], mys[PPB], mzs[PPB];
    __shared__ int ks[PPB];
    __shared__ float tile[CCH * 65];   // [c][p_local]

    int t = threadIdx.x;
    int lane = t & 63;
    int wave = t >> 6;
    int gp0 = blockIdx.x * PPB;        // 64 pillars per block (same batch)

    // per-lane channel constants (issued early; coalesced, L2-hot)
    float w0 = W[0 * CCH + lane], w1 = W[1 * CCH + lane], w2 = W[2 * CCH + lane];
    float w3 = W[3 * CCH + lane], w4 = W[4 * CCH + lane], w5 = W[5 * CCH + lane];
    float w6 = W[6 * CCH + lane], w7 = W[7 * CCH + lane], w8 = W[8 * CCH + lane];
    float sc = gamma[lane] * (1.0f / sqrtf(rvar[lane] + BN_EPS));
    float shift = beta[lane] - rmean[lane] * sc;
    float Ac = (w0 + w3 + w6) * sc;
    float Bc = (w1 + w4 + w7) * sc;
    float Cc = (w2 + w5) * sc;
    float s3 = w3 * sc, s4 = w4 * sc, s5 = w5 * sc;
    float s6 = w6 * sc, s7 = w7 * sc, s8 = w8 * sc;

    // ---- phase 1: parallel gather, thread = (pillar, slot) ----
    {
        int p = t >> 2;                // 0..63
        int j = t & 3;                 // 0..3
        int gp = gp0 + p;
        const float4* bk = bucket + (size_t)gp * CAP;
        float4 e = bk[j];              // one 64B line per pillar, 256-wide
        unsigned kc = cnt[gp];
        int k = (kc < CAP) ? (int)kc : CAP;
        int kl = (k < SLOTS) ? k : SLOTS;
        bool valid = j < kl;
        float px = valid ? e.x : 0.f;
        float py = valid ? e.y : 0.f;
        float pz = valid ? e.z : 0.f;
        if (valid) {
            pxs[p * PSTR + j] = e.x;
            pys[p * PSTR + j] = e.y;
            pzs[p * PSTR + j] = e.z;
        }
        px += __shfl_xor(px, 1); py += __shfl_xor(py, 1); pz += __shfl_xor(pz, 1);
        px += __shfl_xor(px, 2); py += __shfl_xor(py, 2); pz += __shfl_xor(pz, 2);
        if (j == 0) {
            for (int jj = SLOTS; jj < k; ++jj) {   // rare tail
                float4 et = bk[jj];
                px += et.x; py += et.y; pz += et.z;
            }
            ks[p] = k;
            float fk = (k > 0) ? (float)k : 1.0f;
            mxs[p] = px / fk; mys[p] = py / fk; mzs[p] = pz / fk;
        }
    }
    __syncthreads();

    // ---- phase 2: wave-per-pillar, lane = channel, folded PFN ----
    for (int it = 0; it < 16; ++it) {
        int ppl = wave * 16 + it;
        int k = ks[ppl];
        float acc = 0.0f;
        if (k > 0) {
            float mx = mxs[ppl], my = mys[ppl], mz = mzs[ppl];
            int pid = (gp0 + ppl) & (NSEG - 1);
            float ctx = ((float)(pid & (NXg - 1)) + 0.5f) * VOXX + PCMINX;
            float cty = ((float)(pid >> 9) + 0.5f) * VOXY + PCMINY;
            float D = shift;
            D = fmaf(-mx, s3, D); D = fmaf(-my, s4, D); D = fmaf(-mz, s5, D);
            D = fmaf(-ctx, s6, D); D = fmaf(-cty, s7, D);
            int kl = (k < SLOTS) ? k : SLOTS;
            for (int j = 0; j < kl; ++j) {
                float x = pxs[ppl * PSTR + j];
                float y = pys[ppl * PSTR + j];
                float z = pzs[ppl * PSTR + j];
                float cz = floorf((z - PCMINZ) * RECIPZ);
                float ctz = (cz + 0.5f) * VOXZ + PCMINZ;
                float h = fmaf(x, Ac, fmaf(y, Bc, fmaf(z, Cc, fmaf(z - ctz, s8, D))));
                acc += fmaxf(h, 0.0f);
            }
            for (int j = SLOTS; j < k; ++j) {      // rare overflow path
                float4 e = bucket[(size_t)(gp0 + ppl) * CAP + j];
                float cz = floorf((e.z - PCMINZ) * RECIPZ);
                float ctz = (cz + 0.5f) * VOXZ + PCMINZ;
                float h = fmaf(e.x, Ac, fmaf(e.y, Bc, fmaf(e.z, Cc,
                              fmaf(e.z - ctz, s8, D))));
                acc += fmaxf(h, 0.0f);
            }
            acc /= (float)k;
        }
        tile[lane * 65 + ppl] = acc;
    }
    __syncthreads();

    // ---- phase 3: coalesced float4 write-out (64 rows x 16 float4) ----
    int b = gp0 >> 18;                 // NSEG = 2^18
    int pbatch = gp0 & (NSEG - 1);
    size_t obase = (size_t)b * CCH * NSEG + (size_t)pbatch;
    for (int jj = 0; jj < 4; ++jj) {
        int idx = jj * 256 + t;
        int c = idx >> 4;              // channel row 0..63
        int q = idx & 15;              // float4 within row
        float4 v;
        v.x = tile[c * 65 + q * 4 + 0];
        v.y = tile[c * 65 + q * 4 + 1];
        v.z = tile[c * 65 + q * 4 + 2];
        v.w = tile[c * 65 + q * 4 + 3];
        *reinterpret_cast<float4*>(out + obase + (size_t)c * NSEG + q * 4) = v;
    }
}

extern "C" void kernel_launch(void* const* d_in, const int* in_sizes, int n_in,
                              void* d_out, int out_size, void* d_ws, size_t ws_size,
                              hipStream_t stream) {
    const float* points = (const float*)d_in[0];
    const float* W      = (const float*)d_in[1];
    const float* gamma  = (const float*)d_in[2];
    const float* beta   = (const float*)d_in[3];
    const float* rmean  = (const float*)d_in[4];
    const float* rvar   = (const float*)d_in[5];
    float* out = (float*)d_out;

    int B = out_size / (CCH * NSEG);          // 2
    int N = in_sizes[0] / (3 * B);            // 100000
    int BN = B * NSEG;                        // 524288
    int total_pts = B * N;

    // workspace: cnt [BN] u32 (2 MB) + bucket [BN*CAP] float4 (134 MB)
    unsigned* cnt  = (unsigned*)d_ws;
    float4* bucket = (float4*)(cnt + BN);

    hipMemsetAsync(cnt, 0, (size_t)BN * sizeof(unsigned), stream);

    int blk = 256;
    int grd_pts = (total_pts + blk - 1) / blk;
    k1_bin<<<grd_pts, blk, 0, stream>>>(points, cnt, bucket, B, N);
    k4_compute<<<BN / PPB, blk, 0, stream>>>(cnt, bucket, W, gamma, beta,
                                             rmean, rvar, out);
}

// Round 11
// 47.886 us; speedup vs baseline: 1.5027x; 1.0436x over previous
//
#include <hip/hip_runtime.h>
#include <math.h>

#define NXg 512
#define NYg 512
#define NSEG (NXg * NYg)   // 262144 = 2^18
#define CCH 64
#define CAP 16             // total capacity per pillar (first + 15 ext)
#define ECAP 15            // ext slots per pillar
#define SLOTS 4            // points staged in LDS per pillar (k>4 -> global ext)
#define PSTR 5             // LDS point-slot stride
#define PPB 64             // pillars per block
#define BN_EPS 1e-3f

// grid constants (f32, as in the reference arrays)
#define PCMINX (-51.2f)
#define PCMINY (-51.2f)
#define PCMINZ (-3.0f)
#define PCMAXX (51.2f)
#define PCMAXY (51.2f)
#define PCMAXZ (3.0f)
#define VOXX (0.2f)
#define VOXY (0.2f)
#define VOXZ (6.0f)

// f32-exact reciprocals (XLA fast-math computes (p-min)*(1/voxel) in f32).
#define RECIPX 5.0f
#define RECIPY 5.0f
#define RECIPZ (__uint_as_float(0x3E2AAAABu))   // (float)(1/6.0f)

__device__ __forceinline__ int calc_pid(float x, float y, float z) {
    bool in_range = (x >= PCMINX) && (x < PCMAXX) &&
                    (y >= PCMINY) && (y < PCMAXY) &&
                    (z >= PCMINZ) && (z < PCMAXZ);
    if (!in_range) return -1;
    int cx = (int)floorf((x - PCMINX) * RECIPX);
    int cy = (int)floorf((y - PCMINY) * RECIPY);
    int p = cy * NXg + cx;
    return (p >= 0 && p < NSEG) ? p : -1;
}

// K1: point 0 of each pillar -> first[gp]; points 1..15 -> ext[gp*15 + slot-1].
__global__ void k1_bin(const float* __restrict__ pts, unsigned* __restrict__ cnt,
                       float4* __restrict__ first, float4* __restrict__ ext,
                       int B, int N) {
    int i = blockIdx.x * blockDim.x + threadIdx.x;
    if (i >= B * N) return;
    const float* p = pts + (size_t)i * 3;
    float x = p[0], y = p[1], z = p[2];
    int pd = calc_pid(x, y, z);
    if (pd < 0) return;
    int b = i / N;
    int g = b * NSEG + pd;
    unsigned slot = atomicAdd(&cnt[g], 1u);
    float4 e; e.x = x; e.y = y; e.z = z; e.w = 0.0f;
    if (slot == 0) first[g] = e;
    else if (slot < CAP) ext[(size_t)g * ECAP + (slot - 1)] = e;
}

// K4: block = 64 pillars. Phase 1 (1 wave): per-pillar cnt+first loaded as
// independent pairs (single latency hop); ext touched only for k>=2 (~3%).
// Phase 2: wave-per-pillar, lane-per-channel folded PFN (weights in regs).
// Phase 3: coalesced float4 canvas write (every element written).
__global__ void __launch_bounds__(256) k4_compute(
    const unsigned* __restrict__ cnt, const float4* __restrict__ first,
    const float4* __restrict__ ext,
    const float* __restrict__ W, const float* __restrict__ gamma,
    const float* __restrict__ beta, const float* __restrict__ rmean,
    const float* __restrict__ rvar, float* __restrict__ out) {
    __shared__ float pxs[PPB * PSTR];
    __shared__ float pys[PPB * PSTR];
    __shared__ float pzs[PPB * PSTR];
    __shared__ float mxs[PPB], mys[PPB], mzs[PPB];
    __shared__ int ks[PPB];
    __shared__ float tile[CCH * 65];   // [c][p_local]

    int t = threadIdx.x;
    int lane = t & 63;
    int wave = t >> 6;
    int gp0 = blockIdx.x * PPB;        // 64 pillars per block (same batch)

    // per-lane channel constants (coalesced, L2-hot)
    float w0 = W[0 * CCH + lane], w1 = W[1 * CCH + lane], w2 = W[2 * CCH + lane];
    float w3 = W[3 * CCH + lane], w4 = W[4 * CCH + lane], w5 = W[5 * CCH + lane];
    float w6 = W[6 * CCH + lane], w7 = W[7 * CCH + lane], w8 = W[8 * CCH + lane];
    float sc = gamma[lane] * (1.0f / sqrtf(rvar[lane] + BN_EPS));
    float shift = beta[lane] - rmean[lane] * sc;
    float Ac = (w0 + w3 + w6) * sc;
    float Bc = (w1 + w4 + w7) * sc;
    float Cc = (w2 + w5) * sc;
    float s3 = w3 * sc, s4 = w4 * sc, s5 = w5 * sc;
    float s6 = w6 * sc, s7 = w7 * sc, s8 = w8 * sc;

    // ---- phase 1: lane-per-pillar; cnt+first independent loads ----
    if (t < PPB) {
        int gp = gp0 + t;
        float4 f0 = first[gp];         // both issued before either resolves
        unsigned kc = cnt[gp];
        int k = (kc < CAP) ? (int)kc : CAP;
        ks[t] = k;
        float sx = 0.f, sy = 0.f, sz = 0.f;
        if (k > 0) {
            sx = f0.x; sy = f0.y; sz = f0.z;
            pxs[t * PSTR + 0] = f0.x;
            pys[t * PSTR + 0] = f0.y;
            pzs[t * PSTR + 0] = f0.z;
            const float4* ex = ext + (size_t)gp * ECAP;
            for (int j = 1; j < k; ++j) {   // ~3% of pillars reach here
                float4 e = ex[j - 1];
                if (j < SLOTS) {
                    pxs[t * PSTR + j] = e.x;
                    pys[t * PSTR + j] = e.y;
                    pzs[t * PSTR + j] = e.z;
                }
                sx += e.x; sy += e.y; sz += e.z;
            }
        }
        float fk = (k > 0) ? (float)k : 1.0f;
        mxs[t] = sx / fk; mys[t] = sy / fk; mzs[t] = sz / fk;
    }
    __syncthreads();

    // ---- phase 2: wave-per-pillar, lane = channel, folded PFN ----
    for (int it = 0; it < 16; ++it) {
        int ppl = wave * 16 + it;
        int k = ks[ppl];
        float acc = 0.0f;
        if (k > 0) {
            float mx = mxs[ppl], my = mys[ppl], mz = mzs[ppl];
            int pid = (gp0 + ppl) & (NSEG - 1);
            float ctx = ((float)(pid & (NXg - 1)) + 0.5f) * VOXX + PCMINX;
            float cty = ((float)(pid >> 9) + 0.5f) * VOXY + PCMINY;
            float D = shift;
            D = fmaf(-mx, s3, D); D = fmaf(-my, s4, D); D = fmaf(-mz, s5, D);
            D = fmaf(-ctx, s6, D); D = fmaf(-cty, s7, D);
            int kl = (k < SLOTS) ? k : SLOTS;
            for (int j = 0; j < kl; ++j) {
                float x = pxs[ppl * PSTR + j];
                float y = pys[ppl * PSTR + j];
                float z = pzs[ppl * PSTR + j];
                float cz = floorf((z - PCMINZ) * RECIPZ);
                float ctz = (cz + 0.5f) * VOXZ + PCMINZ;
                float h = fmaf(x, Ac, fmaf(y, Bc, fmaf(z, Cc, fmaf(z - ctz, s8, D))));
                acc += fmaxf(h, 0.0f);
            }
            for (int j = SLOTS; j < k; ++j) {      // ~never taken
                float4 e = ext[(size_t)(gp0 + ppl) * ECAP + (j - 1)];
                float cz = floorf((e.z - PCMINZ) * RECIPZ);
                float ctz = (cz + 0.5f) * VOXZ + PCMINZ;
                float h = fmaf(e.x, Ac, fmaf(e.y, Bc, fmaf(e.z, Cc,
                              fmaf(e.z - ctz, s8, D))));
                acc += fmaxf(h, 0.0f);
            }
            acc /= (float)k;
        }
        tile[lane * 65 + ppl] = acc;
    }
    __syncthreads();

    // ---- phase 3: coalesced float4 write-out (64 rows x 16 float4) ----
    int b = gp0 >> 18;                 // NSEG = 2^18
    int pbatch = gp0 & (NSEG - 1);
    size_t obase = (size_t)b * CCH * NSEG + (size_t)pbatch;
    for (int jj = 0; jj < 4; ++jj) {
        int idx = jj * 256 + t;
        int c = idx >> 4;              // channel row 0..63
        int q = idx & 15;              // float4 within row
        float4 v;
        v.x = tile[c * 65 + q * 4 + 0];
        v.y = tile[c * 65 + q * 4 + 1];
        v.z = tile[c * 65 + q * 4 + 2];
        v.w = tile[c * 65 + q * 4 + 3];
        *reinterpret_cast<float4*>(out + obase + (size_t)c * NSEG + q * 4) = v;
    }
}

extern "C" void kernel_launch(void* const* d_in, const int* in_sizes, int n_in,
                              void* d_out, int out_size, void* d_ws, size_t ws_size,
                              hipStream_t stream) {
    const float* points = (const float*)d_in[0];
    const float* W      = (const float*)d_in[1];
    const float* gamma  = (const float*)d_in[2];
    const float* beta   = (const float*)d_in[3];
    const float* rmean  = (const float*)d_in[4];
    const float* rvar   = (const float*)d_in[5];
    float* out = (float*)d_out;

    int B = out_size / (CCH * NSEG);          // 2
    int N = in_sizes[0] / (3 * B);            // 100000
    int BN = B * NSEG;                        // 524288
    int total_pts = B * N;

    // workspace: cnt [BN] u32 (2 MB) + first [BN] float4 (8.4 MB)
    //          + ext [BN*15] float4 (126 MB)
    unsigned* cnt = (unsigned*)d_ws;
    float4* first = (float4*)(cnt + BN);
    float4* ext   = first + BN;

    hipMemsetAsync(cnt, 0, (size_t)BN * sizeof(unsigned), stream);

    int blk = 256;
    int grd_pts = (total_pts + blk - 1) / blk;
    k1_bin<<<grd_pts, blk, 0, stream>>>(points, cnt, first, ext, B, N);
    k4_compute<<<BN / PPB, blk, 0, stream>>>(cnt, first, ext, W, gamma, beta,
                                             rmean, rvar, out);
}